// Round 1
// baseline (105.060 us; speedup 1.0000x reference)
//
#include <hip/hip_runtime.h>

// 2-level separable db4 DWT, pywt 'symmetric' mode, fused single kernel.
// x: (8, 512, 512, 16) f32; out: concat(aa, ad, da, dd) each (8, 259, 259, 16) f32.

constexpr int N  = 512;   // spatial size along both transform axes
constexpr int ON = 259;   // (N + 8 - 1) / 2
constexpr int CH = 16;    // channels (fastest-varying dim)
constexpr int NB = 8;     // batch
constexpr int LDS_STRIDE = 20; // CH padded (breaks 16-word bank stride, keeps 16B align)

__global__ __launch_bounds__(256) void dwt2_fused(
    const float* __restrict__ x, const float* __restrict__ dec_lo,
    float* __restrict__ out)
{
  const int i = blockIdx.x;   // output row index (0..ON-1)
  const int b = blockIdx.y;   // batch

  __shared__ float a_row[N * LDS_STRIDE];  // 40 KB
  __shared__ float d_row[N * LDS_STRIDE];  // 40 KB

  // Reversed decomposition filters (pywt downsampling correlation).
  float lo_rev[8], hi_rev[8];
#pragma unroll
  for (int m = 0; m < 8; ++m) lo_rev[m] = dec_lo[7 - m];
#pragma unroll
  for (int m = 0; m < 8; ++m) hi_rev[m] = (m & 1) ? -dec_lo[m] : dec_lo[m];

  // The 8 input rows feeding output row i (symmetric extension).
  int rows[8];
#pragma unroll
  for (int m = 0; m < 8; ++m) {
    int r = 2 * i + m - 6;
    r = (r < 0) ? (-r - 1) : r;
    r = (r >= N) ? (2 * N - 1 - r) : r;
    rows[m] = r;
  }

  const float* xb = x + (size_t)b * N * N * CH;
  const int t = threadIdx.x;

  // ---- Stage A: vertical DWT (axis -3) of 8 rows -> one intermediate row in LDS
  for (int v = t; v < N * CH / 4; v += 256) {   // 2048 float4s
    const int c   = v >> 2;         // column 0..511
    const int ch0 = (v & 3) * 4;    // channel 0,4,8,12
    float alx = 0.f, aly = 0.f, alz = 0.f, alw = 0.f;
    float ahx = 0.f, ahy = 0.f, ahz = 0.f, ahw = 0.f;
#pragma unroll
    for (int m = 0; m < 8; ++m) {
      const float4 s = *reinterpret_cast<const float4*>(
          xb + (size_t)rows[m] * (N * CH) + (size_t)v * 4);
      alx += lo_rev[m] * s.x; aly += lo_rev[m] * s.y;
      alz += lo_rev[m] * s.z; alw += lo_rev[m] * s.w;
      ahx += hi_rev[m] * s.x; ahy += hi_rev[m] * s.y;
      ahz += hi_rev[m] * s.z; ahw += hi_rev[m] * s.w;
    }
    float4 fa; fa.x = alx; fa.y = aly; fa.z = alz; fa.w = alw;
    float4 fd; fd.x = ahx; fd.y = ahy; fd.z = ahz; fd.w = ahw;
    *reinterpret_cast<float4*>(&a_row[c * LDS_STRIDE + ch0]) = fa;
    *reinterpret_cast<float4*>(&d_row[c * LDS_STRIDE + ch0]) = fd;
  }
  __syncthreads();

  // ---- Stage B: horizontal DWT (axis -2) from LDS -> 4 subbands
  const size_t OUTSZ = (size_t)NB * ON * ON * CH;
  for (int v = t; v < ON * CH / 4; v += 256) {  // 1036 float4s
    const int j   = v >> 2;        // output col 0..258
    const int ch0 = (v & 3) * 4;
    float aax=0.f, aay=0.f, aaz=0.f, aaw=0.f;
    float adx=0.f, ady=0.f, adz=0.f, adw=0.f;
    float dax=0.f, day=0.f, daz=0.f, daw=0.f;
    float ddx=0.f, ddy=0.f, ddz=0.f, ddw=0.f;
#pragma unroll
    for (int m = 0; m < 8; ++m) {
      int c = 2 * j + m - 6;
      c = (c < 0) ? (-c - 1) : c;
      c = (c >= N) ? (2 * N - 1 - c) : c;
      const float4 av = *reinterpret_cast<const float4*>(&a_row[c * LDS_STRIDE + ch0]);
      const float4 dv = *reinterpret_cast<const float4*>(&d_row[c * LDS_STRIDE + ch0]);
      const float lw = lo_rev[m], hw = hi_rev[m];
      aax += lw * av.x; aay += lw * av.y; aaz += lw * av.z; aaw += lw * av.w;
      adx += hw * av.x; ady += hw * av.y; adz += hw * av.z; adw += hw * av.w;
      dax += lw * dv.x; day += lw * dv.y; daz += lw * dv.z; daw += lw * dv.w;
      ddx += hw * dv.x; ddy += hw * dv.y; ddz += hw * dv.z; ddw += hw * dv.w;
    }
    const size_t o = (((size_t)b * ON + i) * ON + j) * CH + ch0;
    float4 faa; faa.x = aax; faa.y = aay; faa.z = aaz; faa.w = aaw;
    float4 fad; fad.x = adx; fad.y = ady; fad.z = adz; fad.w = adw;
    float4 fda; fda.x = dax; fda.y = day; fda.z = daz; fda.w = daw;
    float4 fdd; fdd.x = ddx; fdd.y = ddy; fdd.z = ddz; fdd.w = ddw;
    *reinterpret_cast<float4*>(out + o)             = faa;
    *reinterpret_cast<float4*>(out + OUTSZ + o)     = fad;
    *reinterpret_cast<float4*>(out + 2 * OUTSZ + o) = fda;
    *reinterpret_cast<float4*>(out + 3 * OUTSZ + o) = fdd;
  }
}

extern "C" void kernel_launch(void* const* d_in, const int* in_sizes, int n_in,
                              void* d_out, int out_size, void* d_ws, size_t ws_size,
                              hipStream_t stream) {
  const float* x      = (const float*)d_in[0];
  const float* dec_lo = (const float*)d_in[1];
  float* out          = (float*)d_out;
  dim3 grid(ON, NB);
  dwt2_fused<<<grid, 256, 0, stream>>>(x, dec_lo, out);
}

// Round 2
// 59.683 us; speedup vs baseline: 1.7603x; 1.7603x over previous
//
#include <hip/hip_runtime.h>

// 2-level separable db4 DWT, pywt 'symmetric', fused, rolling-row version.
// x: (8, 512, 512, 16) f32 -> out: concat(aa, ad, da, dd), each (8, 259, 259, 16) f32.
//
// Grid: (col-band, row-segment, batch). Each block owns W=64 input columns
// (covering JB=29 output columns + 6-col halo) and RS=22 output rows.
// Vertical DWT: per-thread register FIFO of the 8 live input rows (2 new
// global row-loads per output row). Horizontal DWT: via a 10 KB LDS stage.

constexpr int N  = 512;
constexpr int ON = 259;          // (N + 8 - 1) / 2
constexpr int CH = 16;
constexpr int NB = 8;
constexpr int JB = 29;           // output cols per band
constexpr int BANDS = 9;         // 9*29 = 261 >= 259
constexpr int RS = 22;           // output rows per segment
constexpr int SEGS = 12;         // 12*22 = 264 >= 259
constexpr int W  = 2 * JB + 6;   // 64 input cols per band (exact span of stage B)
constexpr int LSTR = 20;         // padded channel stride (breaks bank stride, 16B-aligned)

__device__ __forceinline__ int refl(int r) {
  r = (r < 0) ? (-r - 1) : r;
  return (r >= N) ? (2 * N - 1 - r) : r;
}

__global__ __launch_bounds__(256, 4) void dwt2_ring(
    const float* __restrict__ x, const float* __restrict__ dec_lo,
    float* __restrict__ out)
{
  const int band = blockIdx.x, seg = blockIdx.y, b = blockIdx.z;
  const int j0 = band * JB;
  const int i0 = seg * RS;
  const int i1 = min(i0 + RS, ON);
  const int t  = threadIdx.x;
  const int tc = t >> 2;             // column within band (0..63)
  const int tch = (t & 3) << 2;      // channel group (0,4,8,12)

  __shared__ float a_buf[W * LSTR];  // 5 KB
  __shared__ float d_buf[W * LSTR];  // 5 KB

  float lo[8], hi[8];
#pragma unroll
  for (int m = 0; m < 8; ++m) lo[m] = dec_lo[7 - m];
#pragma unroll
  for (int m = 0; m < 8; ++m) hi[m] = (m & 1) ? -dec_lo[m] : dec_lo[m];

  // This thread's input column (with symmetric reflection at image edges).
  const int gc = refl(2 * j0 - 6 + tc);
  const float* xb   = x + (size_t)b * N * N * CH;
  const float* colp = xb + (size_t)gc * CH + tch;

  auto ldrow = [&](int r) -> float4 {
    return *reinterpret_cast<const float4*>(colp + (size_t)refl(r) * (N * CH));
  };

  // Warm the 8-row register FIFO for output row i0 (rows 2*i0-6 .. 2*i0+1).
  float4 f[8];
#pragma unroll
  for (int m = 0; m < 8; ++m) f[m] = ldrow(2 * i0 - 6 + m);

  // Stage-B thread mapping (fixed per thread). Threads 0..115 -> aa/ad from
  // a_buf; 116..231 -> da/dd from d_buf; 232..255 idle in stage B.
  const int  sb  = (t >= 116);
  const int  p   = sb ? (t - 116) : t;
  const int  jr  = p >> 2;
  const int  bch = (p & 3) << 2;
  const int  j   = j0 + jr;
  const bool wr  = (t < 232) && (j < ON);
  const float* src = sb ? d_buf : a_buf;
  const size_t OUTSZ = (size_t)NB * ON * ON * CH;
  float* o_lo = out + (size_t)(2 * sb) * OUTSZ;   // aa or da
  float* o_hi = o_lo + OUTSZ;                     // ad or dd

  for (int i = i0; i < i1; ++i) {
    // ---- Stage A: vertical DWT from the register FIFO -> LDS
    float4 av = {0.f, 0.f, 0.f, 0.f}, dv = {0.f, 0.f, 0.f, 0.f};
#pragma unroll
    for (int m = 0; m < 8; ++m) {
      av.x += lo[m] * f[m].x; av.y += lo[m] * f[m].y;
      av.z += lo[m] * f[m].z; av.w += lo[m] * f[m].w;
      dv.x += hi[m] * f[m].x; dv.y += hi[m] * f[m].y;
      dv.z += hi[m] * f[m].z; dv.w += hi[m] * f[m].w;
    }
    *reinterpret_cast<float4*>(&a_buf[tc * LSTR + tch]) = av;
    *reinterpret_cast<float4*>(&d_buf[tc * LSTR + tch]) = dv;

    // Shift FIFO and issue next 2 row-loads now; latency hides under stage B.
#pragma unroll
    for (int k = 0; k < 6; ++k) f[k] = f[k + 2];
    if (i + 1 < i1) {
      f[6] = ldrow(2 * i + 2);
      f[7] = ldrow(2 * i + 3);
    }

    __syncthreads();

    // ---- Stage B: horizontal DWT from LDS -> 2 subbands per thread
    if (wr) {
      float4 aL = {0.f, 0.f, 0.f, 0.f}, aH = {0.f, 0.f, 0.f, 0.f};
#pragma unroll
      for (int m = 0; m < 8; ++m) {
        const float4 s = *reinterpret_cast<const float4*>(
            &src[(2 * jr + m) * LSTR + bch]);
        aL.x += lo[m] * s.x; aL.y += lo[m] * s.y;
        aL.z += lo[m] * s.z; aL.w += lo[m] * s.w;
        aH.x += hi[m] * s.x; aH.y += hi[m] * s.y;
        aH.z += hi[m] * s.z; aH.w += hi[m] * s.w;
      }
      const size_t o = (((size_t)b * ON + i) * ON + j) * CH + bch;
      *reinterpret_cast<float4*>(o_lo + o) = aL;
      *reinterpret_cast<float4*>(o_hi + o) = aH;
    }
    __syncthreads();
  }
}

extern "C" void kernel_launch(void* const* d_in, const int* in_sizes, int n_in,
                              void* d_out, int out_size, void* d_ws, size_t ws_size,
                              hipStream_t stream) {
  const float* x      = (const float*)d_in[0];
  const float* dec_lo = (const float*)d_in[1];
  float* out          = (float*)d_out;
  dim3 grid(BANDS, SEGS, NB);
  dwt2_ring<<<grid, 256, 0, stream>>>(x, dec_lo, out);
}

// Round 3
// 59.525 us; speedup vs baseline: 1.7650x; 1.0026x over previous
//
#include <hip/hip_runtime.h>

// 2-level separable db4 DWT, pywt 'symmetric', fused, rolling-row version v3.
// x: (8, 512, 512, 16) f32 -> out: concat(aa, ad, da, dd), each (8, 259, 259, 16) f32.
//
// Grid: (col-band, row-segment, batch) = (9, 33, 8) = 2376 blocks, 256 thr.
// Each block: W=64 input columns (JB=29 output cols + halo), RS=8 output rows.
// Vertical DWT via per-thread register FIFO (2 new row-loads per output row);
// horizontal DWT via a double-buffered 20 KB LDS stage (1 barrier per row).

constexpr int N  = 512;
constexpr int ON = 259;          // (N + 8 - 1) / 2
constexpr int CH = 16;
constexpr int NB = 8;
constexpr int JB = 29;           // output cols per band
constexpr int BANDS = 9;         // 9*29 = 261 >= 259
constexpr int RS = 8;            // output rows per segment
constexpr int SEGS = 33;         // 33*8 = 264 >= 259
constexpr int W  = 2 * JB + 6;   // 64 input cols per band (exact span of stage B)
constexpr int LSTR = 20;         // padded channel stride (breaks bank stride, 16B-aligned)

__device__ __forceinline__ int refl(int r) {
  r = (r < 0) ? (-r - 1) : r;
  return (r >= N) ? (2 * N - 1 - r) : r;
}

__global__ __launch_bounds__(256) void dwt2_ring(
    const float* __restrict__ x, const float* __restrict__ dec_lo,
    float* __restrict__ out)
{
  const int band = blockIdx.x, seg = blockIdx.y, b = blockIdx.z;
  const int j0 = band * JB;
  const int i0 = seg * RS;
  const int i1 = min(i0 + RS, ON);
  const int t  = threadIdx.x;
  const int tc = t >> 2;             // column within band (0..63)
  const int tch = (t & 3) << 2;      // channel group (0,4,8,12)

  __shared__ float a_buf[2][W * LSTR];  // 2 x 5 KB
  __shared__ float d_buf[2][W * LSTR];  // 2 x 5 KB

  float lo[8], hi[8];
#pragma unroll
  for (int m = 0; m < 8; ++m) lo[m] = dec_lo[7 - m];
#pragma unroll
  for (int m = 0; m < 8; ++m) hi[m] = (m & 1) ? -dec_lo[m] : dec_lo[m];

  // This thread's input column (with symmetric reflection at image edges).
  const int gc = refl(2 * j0 - 6 + tc);
  const float* xb   = x + (size_t)b * N * N * CH;
  const float* colp = xb + (size_t)gc * CH + tch;

  auto ldrow = [&](int r) -> float4 {
    return *reinterpret_cast<const float4*>(colp + (size_t)refl(r) * (N * CH));
  };

  // Warm the 8-row register FIFO for output row i0 (rows 2*i0-6 .. 2*i0+1).
  float4 f[8];
#pragma unroll
  for (int m = 0; m < 8; ++m) f[m] = ldrow(2 * i0 - 6 + m);

  // Stage-B thread mapping (fixed per thread). Threads 0..115 -> aa/ad from
  // a_buf; 116..231 -> da/dd from d_buf; 232..255 idle in stage B.
  const int  sb  = (t >= 116);
  const int  p   = sb ? (t - 116) : t;
  const int  jr  = p >> 2;
  const int  bch = (p & 3) << 2;
  const int  j   = j0 + jr;
  const bool wr  = (t < 232) && (j < ON);
  const size_t OUTSZ = (size_t)NB * ON * ON * CH;
  float* o_lo = out + (size_t)(2 * sb) * OUTSZ;   // aa or da
  float* o_hi = o_lo + OUTSZ;                     // ad or dd

  int cur = 0;
  for (int i = i0; i < i1; ++i, cur ^= 1) {
    // ---- Stage A: vertical DWT from the register FIFO
    float4 av = {0.f, 0.f, 0.f, 0.f}, dv = {0.f, 0.f, 0.f, 0.f};
#pragma unroll
    for (int m = 0; m < 8; ++m) {
      av.x += lo[m] * f[m].x; av.y += lo[m] * f[m].y;
      av.z += lo[m] * f[m].z; av.w += lo[m] * f[m].w;
      dv.x += hi[m] * f[m].x; dv.y += hi[m] * f[m].y;
      dv.z += hi[m] * f[m].z; dv.w += hi[m] * f[m].w;
    }

    // Shift FIFO and issue next 2 row-loads; they overlap the LDS writes,
    // the barrier, and stage B (first needed at next iteration's stage A).
#pragma unroll
    for (int k = 0; k < 6; ++k) f[k] = f[k + 2];
    if (i + 1 < i1) {
      f[6] = ldrow(2 * i + 2);
      f[7] = ldrow(2 * i + 3);
    }

    // Stage-A results -> current LDS buffer (next iter uses the other one,
    // so a single barrier per iteration suffices; reuse of this buffer at
    // i+2 is separated from stage-B reads at i by the barrier at i+1).
    *reinterpret_cast<float4*>(&a_buf[cur][tc * LSTR + tch]) = av;
    *reinterpret_cast<float4*>(&d_buf[cur][tc * LSTR + tch]) = dv;

    __syncthreads();

    // ---- Stage B: horizontal DWT from LDS -> 2 subbands per thread
    if (wr) {
      const float* src = sb ? d_buf[cur] : a_buf[cur];
      float4 aL = {0.f, 0.f, 0.f, 0.f}, aH = {0.f, 0.f, 0.f, 0.f};
#pragma unroll
      for (int m = 0; m < 8; ++m) {
        const float4 s = *reinterpret_cast<const float4*>(
            &src[(2 * jr + m) * LSTR + bch]);
        aL.x += lo[m] * s.x; aL.y += lo[m] * s.y;
        aL.z += lo[m] * s.z; aL.w += lo[m] * s.w;
        aH.x += hi[m] * s.x; aH.y += hi[m] * s.y;
        aH.z += hi[m] * s.z; aH.w += hi[m] * s.w;
      }
      const size_t o = (((size_t)b * ON + i) * ON + j) * CH + bch;
      *reinterpret_cast<float4*>(o_lo + o) = aL;
      *reinterpret_cast<float4*>(o_hi + o) = aH;
    }
  }
}

extern "C" void kernel_launch(void* const* d_in, const int* in_sizes, int n_in,
                              void* d_out, int out_size, void* d_ws, size_t ws_size,
                              hipStream_t stream) {
  const float* x      = (const float*)d_in[0];
  const float* dec_lo = (const float*)d_in[1];
  float* out          = (float*)d_out;
  dim3 grid(BANDS, SEGS, NB);
  dwt2_ring<<<grid, 256, 0, stream>>>(x, dec_lo, out);
}